// Round 16
// baseline (154.737 us; speedup 1.0000x reference)
//
#include <hip/hip_runtime.h>

typedef __attribute__((__ext_vector_type__(8))) _Float16 f16x8;
typedef __attribute__((__ext_vector_type__(4))) float f32x4;
typedef __attribute__((__ext_vector_type__(4))) int i32x4;

#define HW 56
#define HW2 3136
#define CIN 128
#define COUT 256
#define NB 32
#define NPIX 100352  // 32*3136
#define PH 58        // padded spatial dim (1-px halo)

static __device__ __forceinline__ unsigned short f2h(float f) {
  _Float16 h = (_Float16)f;
  return __builtin_bit_cast(unsigned short, h);
}

#define GLD_LDS16(g, l)                                          \
  __builtin_amdgcn_global_load_lds(                              \
      (const __attribute__((address_space(1))) void*)(g),        \
      (__attribute__((address_space(3))) void*)(l), 16, 0, 0)

// ---- prep_x: x NCHW f32 -> x_pad [32][58][58][128] f16 + channel-sum xs;
//      blocks >= NB*HW zero the 1-px halo ----
__global__ __launch_bounds__(256) void prep_x(const float* __restrict__ x,
                                              unsigned short* __restrict__ xp,
                                              float* __restrict__ xs) {
  if (blockIdx.x >= NB * HW) {  // halo-zero blocks
    int t = (blockIdx.x - NB * HW) * 256 + threadIdx.x;  // < 32*228*16
    int ck = t & 15;
    int pi = t >> 4;
    int b = pi / 228, r = pi - b * 228;
    int h, w;
    if (r < 58) { h = 0; w = r; }
    else if (r < 116) { h = 57; w = r - 58; }
    else { int q = r - 116; h = 1 + (q >> 1); w = (q & 1) * 57; }
    size_t off = (((size_t)(b * PH + h) * PH + w) << 8) + (ck << 4);
    *reinterpret_cast<i32x4*>((char*)xp + off) = (i32x4){0, 0, 0, 0};
    return;
  }
  __shared__ float tile[CIN * 57];  // [c][w], stride 57 kills bank conflicts
  const int bh = blockIdx.x;        // b*56 + h
  const float* src = x + (size_t)(bh / HW) * CIN * HW2 + (size_t)(bh % HW) * HW;
  for (int idx = threadIdx.x; idx < CIN * HW; idx += 256) {
    int c = idx / HW, w = idx - c * HW;
    tile[c * 57 + w] = src[(size_t)c * HW2 + w];
  }
  __syncthreads();
  unsigned short* dst =
      xp + (((size_t)(bh / HW) * PH + (bh % HW) + 1) * PH + 1) * CIN;
  for (int idx = threadIdx.x; idx < HW * (CIN / 2); idx += 256) {
    int w = idx >> 6;         // pixel within row
    int c = (idx & 63) << 1;  // channel pair
    unsigned lo = f2h(tile[c * 57 + w]);
    unsigned hi = f2h(tile[(c + 1) * 57 + w]);
    *reinterpret_cast<unsigned*>(&dst[w * CIN + c]) = lo | (hi << 16);
  }
  if (threadIdx.x < HW) {
    float s = 0.f;
    for (int c = 0; c < CIN; ++c) s += tile[c * 57 + threadIdx.x];
    xs[(size_t)bh * HW + threadIdx.x] = s;
  }
}

// ---- prep_w2: core [COUT][CIN][3][3] f32 -> per-fragment 1KB chunks:
// c_id = ((p*2+ch)*16+cb)*2+ko; lane l holds cout=cb*16+(l&15),
// chans ch*64+ko*32+(l>>4)*8..+8. One chunk == one MFMA A-fragment. ----
__global__ __launch_bounds__(256) void prep_w2(const float* __restrict__ core,
                                               unsigned short* __restrict__ w_t2) {
  int tid = blockIdx.x * 256 + threadIdx.x;  // < 576*64
  int l = tid & 63;
  int c_id = tid >> 6;
  int ko = c_id & 1;
  int cb = (c_id >> 1) & 15;
  int pc = c_id >> 5;            // p*2+ch
  int ch = pc & 1, p = pc >> 1;
  int cout = cb * 16 + (l & 15);
  int chan0 = ch * 64 + ko * 32 + (l >> 4) * 8;
  unsigned short v[8];
#pragma unroll
  for (int e = 0; e < 8; ++e)
    v[e] = f2h(core[(size_t)(cout * CIN + chan0 + e) * 9 + p]);
  *reinterpret_cast<i32x4*>(w_t2 + (size_t)tid * 8) =
      *reinterpret_cast<const i32x4*>(v);
}

// ---- periphery stencil on xs ----
__global__ __launch_bounds__(256) void periph_k(const float* __restrict__ xs,
                                                const float* __restrict__ per,
                                                float* __restrict__ po) {
  int n = blockIdx.x * 256 + threadIdx.x;
  int b = n / HW2, r = n - b * HW2;
  int ho = r / HW, wo = r - ho * HW;
  const float* xb = xs + (size_t)b * HW2;
  const int pdy[16] = {0,0,0,0,0,1,1,2,2,3,3,4,4,4,4,4};
  const int pdx[16] = {0,1,2,3,4,0,4,0,4,0,4,0,1,2,3,4};
  float acc = 0.f;
#pragma unroll
  for (int t = 0; t < 16; ++t) {
    int h = ho + pdy[t] - 2, w = wo + pdx[t] - 2;
    if ((unsigned)h < HW && (unsigned)w < HW) acc += per[t] * xb[h * HW + w];
  }
  po[n] = acc;
}

// ---- hybrid implicit-GEMM conv: A via L2 registers, B via LDS pipeline ----
// BM=128 BN=128 BK=64, 4 waves (2M x 2N), wave tile 64x64.
// R16 vs R14/R15:
// (1) ALL barriers are asm volatile("s_barrier":::"memory") — a may-write
//     asm is a two-way code-motion fence, so gld_lds/loads cannot cross
//     (R15's post-timing race = scheduler moving DMA writes across the raw
//     builtin barrier, which is NOT a compiler fence).
// (2) A prefetch distance 1 (named pa/qa, static indexing): per iter
//     {B1; STAGEB(t+1); LOADA(next,t+1); vmcnt(12); B2; ds_read; MFMA(cur)}.
//     Ledger: entry outstanding = stage(t)4+A(t)8 = 12; +12 issued = 24;
//     vmcnt(12) retires exactly stage(t)+A(t) -> B-gate AND this iter's A
//     operands ready in ONE counted wait; nothing newer needs draining
//     before MFMA (R14's compiler self-drain is structurally impossible).
//     stage(t+1)+A(t+1) [12 ops] stay in flight through compute. Only full
//     drain is t=17.
__global__ __launch_bounds__(256, 3) void gemm_k(const unsigned short* __restrict__ xp,
                                                 const unsigned short* __restrict__ w_t2,
                                                 const float* __restrict__ po,
                                                 const float* __restrict__ thresh,
                                                 const float* __restrict__ scale,
                                                 float* __restrict__ out) {
  __shared__ __align__(16) char sMem[2 * 16384];  // B only, double-buffered

  const int tid = threadIdx.x;
  const int lane = tid & 63;
  const int wid = tid >> 6;  // 0..3
  const int wm = wid >> 1;   // 0..1 (cout half of 128)
  const int wn = wid & 1;    // 0..1 (pixel half of 128)

  // XCD-chunked bijective swizzle: nwg=1568=8*196; cout-pair adjacent
  const int bid = blockIdx.x;
  const int sb = (bid & 7) * 196 + (bid >> 3);
  const int m0 = (sb & 1) << 7;   // 0 or 128
  const int n0 = (sb >> 1) << 7;  // pixel tile base

  // ---- B staging addresses (linear LDS dest + inverse-swizzled source) ----
  const int l8 = lane >> 3;  // row within 8-row chunk
  const int ls = lane & 7;   // 16B slot within 128B row
  const int sw = (ls ^ l8) << 4;
  const char* xpc = (const char*)xp;
  int bSrc[4];
#pragma unroll
  for (int c = 0; c < 4; ++c) {
    int n = n0 + wid * 32 + c * 8 + l8;
    int b = n / HW2, rr = n - b * HW2;
    int h = rr / HW, w = rr - h * HW;
    bSrc[c] = ((b * PH + h + 1) * PH + (w + 1)) * 256 + sw;
  }
  const int bDst = wid * 4096;  // 4 chunks x 1KB, wave-uniform

  // ---- A fragment chunk base: frag(i,ko) at tile t:
  //  ((t*16 + cbase + i)*2 + ko)*1024 + lane*16 ----
  const int cbase = (m0 >> 4) + wm * 4;
  const char* wa = (const char*)w_t2 + (lane << 4);

  // ---- B fragment read offsets (swizzled) ----
  int bro[4][2];
#pragma unroll
  for (int j = 0; j < 4; ++j)
#pragma unroll
    for (int ko = 0; ko < 2; ++ko) {
      int rowB = wn * 64 + j * 16 + (lane & 15);
      int boc = ko * 64 + ((lane >> 4) << 4);
      bro[j][ko] = rowB * 128 + (boc ^ ((rowB & 7) << 4));
    }

  auto STAGEB = [&](int buf, int t) {
    const int p = t >> 1;            // tap 0..8
    const int ch = (t & 1) << 7;     // c-half byte offset
    const int dy = p / 3 - 1, dx = p - (p / 3) * 3 - 1;
    const int offB = ((dy * PH + dx) << 8) + ch;
    char* base = sMem + buf * 16384;
#pragma unroll
    for (int c = 0; c < 4; ++c)
      GLD_LDS16(xpc + bSrc[c] + offB, base + bDst + c * 1024);
  };

#define LOADA(A, t)                                                         \
  {                                                                         \
    _Pragma("unroll") for (int i_ = 0; i_ < 4; ++i_)                        \
        _Pragma("unroll") for (int ko_ = 0; ko_ < 2; ++ko_)                 \
        A[i_ * 2 + ko_] = *reinterpret_cast<const f16x8*>(                  \
            wa + (size_t)(((t)*16 + cbase + i_) * 2 + ko_) * 1024);         \
  }

#define BARF() asm volatile("s_barrier" ::: "memory")

#define ITER(CUR, NXT, t)                                                   \
  {                                                                         \
    const char* base = sMem + ((t) & 1) * 16384;                            \
    BARF(); /* B1: all waves done reading buf^1 (iter t-1) */               \
    if ((t) < 17) {                                                         \
      STAGEB(((t) + 1) & 1, (t) + 1);                                       \
      LOADA(NXT, (t) + 1)                                                   \
      asm volatile("s_waitcnt vmcnt(12)" ::: "memory"); /* stage(t)+A(t) */ \
    } else {                                                                \
      asm volatile("s_waitcnt vmcnt(0)" ::: "memory");                      \
    }                                                                       \
    BARF(); /* B2: everyone's stage(t) landed */                            \
    f16x8 bfr[4][2];                                                        \
    _Pragma("unroll") for (int j_ = 0; j_ < 4; ++j_)                        \
        _Pragma("unroll") for (int ko_ = 0; ko_ < 2; ++ko_)                 \
        bfr[j_][ko_] = *reinterpret_cast<const f16x8*>(base + bro[j_][ko_]);\
    _Pragma("unroll") for (int i_ = 0; i_ < 4; ++i_) {                      \
      __builtin_amdgcn_s_setprio(1);                                        \
      _Pragma("unroll") for (int j_ = 0; j_ < 4; ++j_) {                    \
        acc[i_][j_] = __builtin_amdgcn_mfma_f32_16x16x32_f16(               \
            CUR[i_ * 2], bfr[j_][0], acc[i_][j_], 0, 0, 0);                 \
        acc[i_][j_] = __builtin_amdgcn_mfma_f32_16x16x32_f16(               \
            CUR[i_ * 2 + 1], bfr[j_][1], acc[i_][j_], 0, 0, 0);             \
      }                                                                     \
      __builtin_amdgcn_s_setprio(0);                                        \
    }                                                                       \
  }

  f32x4 acc[4][4] = {};
  f16x8 pa[8], qa[8];

  STAGEB(0, 0);
  LOADA(pa, 0)
  __syncthreads();  // full drain: stage(0) landed, pa(0) ready

  for (int tt = 0; tt < 9; ++tt) {
    ITER(pa, qa, 2 * tt)
    ITER(qa, pa, 2 * tt + 1)
  }
#undef ITER
#undef LOADA
#undef BARF

  const float sc = scale[0];
#pragma unroll
  for (int j = 0; j < 4; ++j) {
    int n = n0 + wn * 64 + j * 16 + (lane & 15);
    int b = n / HW2;
    int r = n - b * HW2;  // ho*56+wo
    float pv = po[n];
    float* op = out + (size_t)b * (COUT * HW2) + r;
#pragma unroll
    for (int i = 0; i < 4; ++i) {
      int cl = m0 + wm * 64 + i * 16 + ((lane >> 4) << 2);
      f32x4 th = *reinterpret_cast<const f32x4*>(&thresh[cl]);
#pragma unroll
      for (int q = 0; q < 4; ++q) {
        float cv = acc[i][j][q];
        float g = 1.f / (1.f + __expf(-sc * (cv - th[q])));
        op[(size_t)(cl + q) * HW2] = cv + g * pv;
      }
    }
  }
}

extern "C" void kernel_launch(void* const* d_in, const int* in_sizes, int n_in,
                              void* d_out, int out_size, void* d_ws, size_t ws_size,
                              hipStream_t stream) {
  (void)in_sizes; (void)n_in; (void)out_size; (void)ws_size;
  const float* x      = (const float*)d_in[0];
  const float* core   = (const float*)d_in[1];
  const float* per    = (const float*)d_in[2];
  const float* thresh = (const float*)d_in[3];
  const float* scale  = (const float*)d_in[4];
  float* out = (float*)d_out;

  char* ws = (char*)d_ws;
  unsigned short* xp   = (unsigned short*)ws;                  // 27,557,888 B
  unsigned short* w_t2 = (unsigned short*)(ws + 27557888);     // 589,824 B
  float* xs            = (float*)(ws + 28147712);              // 401,408 B
  float* po            = (float*)(ws + 28549120);              // 401,408 B

  prep_x<<<NB * HW + 456, 256, 0, stream>>>(x, xp, xs);  // +456 halo blocks
  prep_w2<<<(576 * 64) / 256, 256, 0, stream>>>(core, w_t2);
  periph_k<<<NPIX / 256, 256, 0, stream>>>(xs, per, po);
  gemm_k<<<2 * (NPIX / 128), 256, 0, stream>>>(xp, w_t2, po, thresh, scale, out);
}

// Round 17
// 120.956 us; speedup vs baseline: 1.2793x; 1.2793x over previous
//
#include <hip/hip_runtime.h>

typedef __attribute__((__ext_vector_type__(8))) _Float16 f16x8;
typedef __attribute__((__ext_vector_type__(4))) float f32x4;
typedef __attribute__((__ext_vector_type__(4))) int i32x4;

#define HW 56
#define HW2 3136
#define CIN 128
#define COUT 256
#define NB 32
#define NPIX 100352  // 32*3136
#define PH 58        // padded spatial dim (1-px halo)

static __device__ __forceinline__ unsigned short f2h(float f) {
  _Float16 h = (_Float16)f;
  return __builtin_bit_cast(unsigned short, h);
}

#define GLD_LDS16(g, l)                                          \
  __builtin_amdgcn_global_load_lds(                              \
      (const __attribute__((address_space(1))) void*)(g),        \
      (__attribute__((address_space(3))) void*)(l), 16, 0, 0)

// ---- prep_x: x NCHW f32 -> x_pad [32][58][58][128] f16 + channel-sum xs;
//      blocks >= NB*HW zero the 1-px halo ----
__global__ __launch_bounds__(256) void prep_x(const float* __restrict__ x,
                                              unsigned short* __restrict__ xp,
                                              float* __restrict__ xs) {
  if (blockIdx.x >= NB * HW) {  // halo-zero blocks
    int t = (blockIdx.x - NB * HW) * 256 + threadIdx.x;  // < 32*228*16
    int ck = t & 15;
    int pi = t >> 4;
    int b = pi / 228, r = pi - b * 228;
    int h, w;
    if (r < 58) { h = 0; w = r; }
    else if (r < 116) { h = 57; w = r - 58; }
    else { int q = r - 116; h = 1 + (q >> 1); w = (q & 1) * 57; }
    size_t off = (((size_t)(b * PH + h) * PH + w) << 8) + (ck << 4);
    *reinterpret_cast<i32x4*>((char*)xp + off) = (i32x4){0, 0, 0, 0};
    return;
  }
  __shared__ float tile[CIN * 57];  // [c][w], stride 57 kills bank conflicts
  const int bh = blockIdx.x;        // b*56 + h
  const float* src = x + (size_t)(bh / HW) * CIN * HW2 + (size_t)(bh % HW) * HW;
  for (int idx = threadIdx.x; idx < CIN * HW; idx += 256) {
    int c = idx / HW, w = idx - c * HW;
    tile[c * 57 + w] = src[(size_t)c * HW2 + w];
  }
  __syncthreads();
  unsigned short* dst =
      xp + (((size_t)(bh / HW) * PH + (bh % HW) + 1) * PH + 1) * CIN;
  for (int idx = threadIdx.x; idx < HW * (CIN / 2); idx += 256) {
    int w = idx >> 6;         // pixel within row
    int c = (idx & 63) << 1;  // channel pair
    unsigned lo = f2h(tile[c * 57 + w]);
    unsigned hi = f2h(tile[(c + 1) * 57 + w]);
    *reinterpret_cast<unsigned*>(&dst[w * CIN + c]) = lo | (hi << 16);
  }
  if (threadIdx.x < HW) {
    float s = 0.f;
    for (int c = 0; c < CIN; ++c) s += tile[c * 57 + threadIdx.x];
    xs[(size_t)bh * HW + threadIdx.x] = s;
  }
}

// ---- prep_w2: core [COUT][CIN][3][3] f32 -> per-fragment 1KB chunks:
// c_id = ((p*2+ch)*16+cb)*2+ko; lane l holds cout=cb*16+(l&15),
// chans ch*64+ko*32+(l>>4)*8..+8. One chunk == one MFMA A-fragment. ----
__global__ __launch_bounds__(256) void prep_w2(const float* __restrict__ core,
                                               unsigned short* __restrict__ w_t2) {
  int tid = blockIdx.x * 256 + threadIdx.x;  // < 576*64
  int l = tid & 63;
  int c_id = tid >> 6;
  int ko = c_id & 1;
  int cb = (c_id >> 1) & 15;
  int pc = c_id >> 5;            // p*2+ch
  int ch = pc & 1, p = pc >> 1;
  int cout = cb * 16 + (l & 15);
  int chan0 = ch * 64 + ko * 32 + (l >> 4) * 8;
  unsigned short v[8];
#pragma unroll
  for (int e = 0; e < 8; ++e)
    v[e] = f2h(core[(size_t)(cout * CIN + chan0 + e) * 9 + p]);
  *reinterpret_cast<i32x4*>(w_t2 + (size_t)tid * 8) =
      *reinterpret_cast<const i32x4*>(v);
}

// ---- periphery stencil on xs ----
__global__ __launch_bounds__(256) void periph_k(const float* __restrict__ xs,
                                                const float* __restrict__ per,
                                                float* __restrict__ po) {
  int n = blockIdx.x * 256 + threadIdx.x;
  int b = n / HW2, r = n - b * HW2;
  int ho = r / HW, wo = r - ho * HW;
  const float* xb = xs + (size_t)b * HW2;
  const int pdy[16] = {0,0,0,0,0,1,1,2,2,3,3,4,4,4,4,4};
  const int pdx[16] = {0,1,2,3,4,0,4,0,4,0,4,0,1,2,3,4};
  float acc = 0.f;
#pragma unroll
  for (int t = 0; t < 16; ++t) {
    int h = ho + pdy[t] - 2, w = wo + pdx[t] - 2;
    if ((unsigned)h < HW && (unsigned)w < HW) acc += per[t] * xb[h * HW + w];
  }
  po[n] = acc;
}

// ---- wave-private barrier-free implicit-GEMM conv ----
// BM=128 BN=128 BK=64, 4 waves (2M x 2N), wave tile 64x64.
// A: register-loaded from w_t2 L2 chunks (R14's proven half), dist-1 dbuf.
// B: each wave stages the 64 rows IT ALONE reads into its PRIVATE 16KB LDS
//    region (2 x 8KB dbuf, 8 gld_lds/tile). Every K-loop dependency is
//    same-wave: gld_lds -> counted vmcnt -> own ds_read. NO s_barrier
//    between prologue and epilogue; waves free-run (the 36-barrier lockstep
//    tax of R4..R14 is structurally gone).
// Ledger/iter: issue A(t+1)[8]+stage(t+1)[8]=16 new; vmcnt(16) retires
// exactly A(t)+stage(t) -> MFMA operands + B(t) ready in ONE counted wait;
// 16 ops in flight through compute. One "memory" asm per iter (R14's dose —
// R16 showed fencing every barrier poisons codegen). Tail t=17: vmcnt(0).
__global__ __launch_bounds__(256, 2) void gemm_k(const unsigned short* __restrict__ xp,
                                                 const unsigned short* __restrict__ w_t2,
                                                 const float* __restrict__ po,
                                                 const float* __restrict__ thresh,
                                                 const float* __restrict__ scale,
                                                 float* __restrict__ out) {
  __shared__ __align__(16) char sMem[4 * 16384];  // per-wave private 16KB

  const int tid = threadIdx.x;
  const int lane = tid & 63;
  const int wid = tid >> 6;  // 0..3
  const int wm = wid >> 1;   // 0..1 (cout half of 128)
  const int wn = wid & 1;    // 0..1 (pixel half of 128)

  // XCD-chunked bijective swizzle: nwg=1568=8*196; cout-pair adjacent
  const int bid = blockIdx.x;
  const int sb = (bid & 7) * 196 + (bid >> 3);
  const int m0 = (sb & 1) << 7;   // 0 or 128
  const int n0 = (sb >> 1) << 7;  // pixel tile base

  // ---- B staging: wave stages its own rows wn*64 .. wn*64+63 ----
  const int l8 = lane >> 3;  // row within 8-row chunk
  const int ls = lane & 7;   // 16B slot within 128B row
  const int sw = (ls ^ l8) << 4;
  const char* xpc = (const char*)xp;
  int bSrc[8];
#pragma unroll
  for (int c = 0; c < 8; ++c) {
    int n = n0 + wn * 64 + c * 8 + l8;
    int b = n / HW2, rr = n - b * HW2;
    int h = rr / HW, w = rr - h * HW;
    bSrc[c] = ((b * PH + h + 1) * PH + (w + 1)) * 256 + sw;
  }
  char* myLds = sMem + wid * 16384;  // private region

  // ---- A fragment chunk base ----
  const int cbase = (m0 >> 4) + wm * 4;
  const char* wa = (const char*)w_t2 + (lane << 4);

  // ---- B fragment read offsets within private buffer (local rows) ----
  int bro[4][2];
#pragma unroll
  for (int j = 0; j < 4; ++j)
#pragma unroll
    for (int ko = 0; ko < 2; ++ko) {
      int lr = j * 16 + (lane & 15);  // local row 0..63
      int boc = ko * 64 + ((lane >> 4) << 4);
      bro[j][ko] = lr * 128 + (boc ^ ((lr & 7) << 4));
    }

  auto STAGEB = [&](int t) {
    const int p = t >> 1;            // tap 0..8
    const int ch = (t & 1) << 7;     // c-half byte offset
    const int dy = p / 3 - 1, dx = p - (p / 3) * 3 - 1;
    const int offB = ((dy * PH + dx) << 8) + ch;
    char* base = myLds + (t & 1) * 8192;
#pragma unroll
    for (int c = 0; c < 8; ++c)
      GLD_LDS16(xpc + bSrc[c] + offB, base + c * 1024);
  };

#define LOADA(A, t)                                                         \
  {                                                                         \
    _Pragma("unroll") for (int i_ = 0; i_ < 4; ++i_)                        \
        _Pragma("unroll") for (int ko_ = 0; ko_ < 2; ++ko_)                 \
        A[i_ * 2 + ko_] = *reinterpret_cast<const f16x8*>(                  \
            wa + (size_t)(((t)*16 + cbase + i_) * 2 + ko_) * 1024);         \
  }

#define ITER(CUR, NXT, t)                                                   \
  {                                                                         \
    if ((t) < 17) {                                                         \
      LOADA(NXT, (t) + 1)                                                   \
      STAGEB((t) + 1);                                                      \
      asm volatile("s_waitcnt vmcnt(16)" ::: "memory"); /* A(t)+stage(t) */ \
    } else {                                                                \
      asm volatile("s_waitcnt vmcnt(0)" ::: "memory");                      \
    }                                                                       \
    const char* base = myLds + ((t) & 1) * 8192;                            \
    f16x8 bfr[4][2];                                                        \
    _Pragma("unroll") for (int j_ = 0; j_ < 4; ++j_)                        \
        _Pragma("unroll") for (int ko_ = 0; ko_ < 2; ++ko_)                 \
        bfr[j_][ko_] = *reinterpret_cast<const f16x8*>(base + bro[j_][ko_]);\
    _Pragma("unroll") for (int i_ = 0; i_ < 4; ++i_) {                      \
      __builtin_amdgcn_s_setprio(1);                                        \
      _Pragma("unroll") for (int j_ = 0; j_ < 4; ++j_) {                    \
        acc[i_][j_] = __builtin_amdgcn_mfma_f32_16x16x32_f16(               \
            CUR[i_ * 2], bfr[j_][0], acc[i_][j_], 0, 0, 0);                 \
        acc[i_][j_] = __builtin_amdgcn_mfma_f32_16x16x32_f16(               \
            CUR[i_ * 2 + 1], bfr[j_][1], acc[i_][j_], 0, 0, 0);             \
      }                                                                     \
      __builtin_amdgcn_s_setprio(0);                                        \
    }                                                                       \
  }

  f32x4 acc[4][4] = {};
  f16x8 pa[8], qa[8];

  LOADA(pa, 0)
  STAGEB(0);
  asm volatile("s_waitcnt vmcnt(0)" ::: "memory");  // own stage(0)+A(0) done

  for (int tt = 0; tt < 9; ++tt) {
    ITER(pa, qa, 2 * tt)
    ITER(qa, pa, 2 * tt + 1)
  }
#undef ITER
#undef LOADA

  const float sc = scale[0];
#pragma unroll
  for (int j = 0; j < 4; ++j) {
    int n = n0 + wn * 64 + j * 16 + (lane & 15);
    int b = n / HW2;
    int r = n - b * HW2;  // ho*56+wo
    float pv = po[n];
    float* op = out + (size_t)b * (COUT * HW2) + r;
#pragma unroll
    for (int i = 0; i < 4; ++i) {
      int cl = m0 + wm * 64 + i * 16 + ((lane >> 4) << 2);
      f32x4 th = *reinterpret_cast<const f32x4*>(&thresh[cl]);
#pragma unroll
      for (int q = 0; q < 4; ++q) {
        float cv = acc[i][j][q];
        float g = 1.f / (1.f + __expf(-sc * (cv - th[q])));
        op[(size_t)(cl + q) * HW2] = cv + g * pv;
      }
    }
  }
}

extern "C" void kernel_launch(void* const* d_in, const int* in_sizes, int n_in,
                              void* d_out, int out_size, void* d_ws, size_t ws_size,
                              hipStream_t stream) {
  (void)in_sizes; (void)n_in; (void)out_size; (void)ws_size;
  const float* x      = (const float*)d_in[0];
  const float* core   = (const float*)d_in[1];
  const float* per    = (const float*)d_in[2];
  const float* thresh = (const float*)d_in[3];
  const float* scale  = (const float*)d_in[4];
  float* out = (float*)d_out;

  char* ws = (char*)d_ws;
  unsigned short* xp   = (unsigned short*)ws;                  // 27,557,888 B
  unsigned short* w_t2 = (unsigned short*)(ws + 27557888);     // 589,824 B
  float* xs            = (float*)(ws + 28147712);              // 401,408 B
  float* po            = (float*)(ws + 28549120);              // 401,408 B

  prep_x<<<NB * HW + 456, 256, 0, stream>>>(x, xp, xs);  // +456 halo blocks
  prep_w2<<<(576 * 64) / 256, 256, 0, stream>>>(core, w_t2);
  periph_k<<<NPIX / 256, 256, 0, stream>>>(xs, per, po);
  gemm_k<<<2 * (NPIX / 128), 256, 0, stream>>>(xp, w_t2, po, thresh, scale, out);
}

// Round 18
// 110.405 us; speedup vs baseline: 1.4015x; 1.0956x over previous
//
#include <hip/hip_runtime.h>

typedef __attribute__((__ext_vector_type__(8))) _Float16 f16x8;
typedef __attribute__((__ext_vector_type__(4))) float f32x4;
typedef __attribute__((__ext_vector_type__(4))) int i32x4;

#define HW 56
#define HW2 3136
#define CIN 128
#define COUT 256
#define NB 32
#define NPIX 100352  // 32*3136
#define PH 58        // padded spatial dim (1-px halo)

static __device__ __forceinline__ unsigned short f2h(float f) {
  _Float16 h = (_Float16)f;
  return __builtin_bit_cast(unsigned short, h);
}

#define GLD_LDS16(g, l)                                          \
  __builtin_amdgcn_global_load_lds(                              \
      (const __attribute__((address_space(1))) void*)(g),        \
      (__attribute__((address_space(3))) void*)(l), 16, 0, 0)

// ---- prep_x: fused 3-way kernel ----
// blocks [0, NB*HW): x NCHW f32 -> x_pad [32][58][58][128] f16 + channel-sum xs
// blocks [NB*HW, NB*HW+456): zero the 1-px halo of x_pad
// blocks [NB*HW+456, +144): core f32 -> w_t2 per-fragment 1KB chunks
__global__ __launch_bounds__(256) void prep_x(const float* __restrict__ x,
                                              const float* __restrict__ core,
                                              unsigned short* __restrict__ xp,
                                              unsigned short* __restrict__ w_t2,
                                              float* __restrict__ xs) {
  if (blockIdx.x >= NB * HW + 456) {  // prep_w2 branch
    int tid = (blockIdx.x - NB * HW - 456) * 256 + threadIdx.x;  // < 576*64
    int l = tid & 63;
    int c_id = tid >> 6;
    int ko = c_id & 1;
    int cb = (c_id >> 1) & 15;
    int pc = c_id >> 5;  // p*2+ch
    int ch = pc & 1, p = pc >> 1;
    int cout = cb * 16 + (l & 15);
    int chan0 = ch * 64 + ko * 32 + (l >> 4) * 8;
    unsigned short v[8];
#pragma unroll
    for (int e = 0; e < 8; ++e)
      v[e] = f2h(core[(size_t)(cout * CIN + chan0 + e) * 9 + p]);
    *reinterpret_cast<i32x4*>(w_t2 + (size_t)tid * 8) =
        *reinterpret_cast<const i32x4*>(v);
    return;
  }
  if (blockIdx.x >= NB * HW) {  // halo-zero branch
    int t = (blockIdx.x - NB * HW) * 256 + threadIdx.x;  // < 32*228*16
    int ck = t & 15;
    int pi = t >> 4;
    int b = pi / 228, r = pi - b * 228;
    int h, w;
    if (r < 58) { h = 0; w = r; }
    else if (r < 116) { h = 57; w = r - 58; }
    else { int q = r - 116; h = 1 + (q >> 1); w = (q & 1) * 57; }
    size_t off = (((size_t)(b * PH + h) * PH + w) << 8) + (ck << 4);
    *reinterpret_cast<i32x4*>((char*)xp + off) = (i32x4){0, 0, 0, 0};
    return;
  }
  __shared__ float tile[CIN * 57];  // [c][w], stride 57 kills bank conflicts
  const int bh = blockIdx.x;        // b*56 + h
  const float* src = x + (size_t)(bh / HW) * CIN * HW2 + (size_t)(bh % HW) * HW;
  for (int idx = threadIdx.x; idx < CIN * HW; idx += 256) {
    int c = idx / HW, w = idx - c * HW;
    tile[c * 57 + w] = src[(size_t)c * HW2 + w];
  }
  __syncthreads();
  unsigned short* dst =
      xp + (((size_t)(bh / HW) * PH + (bh % HW) + 1) * PH + 1) * CIN;
  for (int idx = threadIdx.x; idx < HW * (CIN / 2); idx += 256) {
    int w = idx >> 6;         // pixel within row
    int c = (idx & 63) << 1;  // channel pair
    unsigned lo = f2h(tile[c * 57 + w]);
    unsigned hi = f2h(tile[(c + 1) * 57 + w]);
    *reinterpret_cast<unsigned*>(&dst[w * CIN + c]) = lo | (hi << 16);
  }
  if (threadIdx.x < HW) {
    float s = 0.f;
    for (int c = 0; c < CIN; ++c) s += tile[c * 57 + threadIdx.x];
    xs[(size_t)bh * HW + threadIdx.x] = s;
  }
}

// ---- periphery stencil on xs ----
__global__ __launch_bounds__(256) void periph_k(const float* __restrict__ xs,
                                                const float* __restrict__ per,
                                                float* __restrict__ po) {
  int n = blockIdx.x * 256 + threadIdx.x;
  int b = n / HW2, r = n - b * HW2;
  int ho = r / HW, wo = r - ho * HW;
  const float* xb = xs + (size_t)b * HW2;
  const int pdy[16] = {0,0,0,0,0,1,1,2,2,3,3,4,4,4,4,4};
  const int pdx[16] = {0,1,2,3,4,0,4,0,4,0,4,0,1,2,3,4};
  float acc = 0.f;
#pragma unroll
  for (int t = 0; t < 16; ++t) {
    int h = ho + pdy[t] - 2, w = wo + pdx[t] - 2;
    if ((unsigned)h < HW && (unsigned)w < HW) acc += per[t] * xb[h * HW + w];
  }
  po[n] = acc;
}

// ---- hybrid implicit-GEMM conv: A via L2 registers, B via LDS pipeline ----
// (R14's validated kernel, byte-identical.)
// BM=128 BN=128 BK=64, 4 waves (2M x 2N), wave tile 64x64. Per K-tile per
// wave: 4 gld_lds (B stage) + 8 coalesced global A-frag loads (w_t2 1KB
// chunks, L2-resident, single-buffered) + 8 ds_read_b128 + 32 MFMA.
// vmcnt ledger (issue order: ..., stage(t)[4], [iter t:] stage(t+1)[4],
// A(t)[8], gate): retire stage(t) => keep 12 newest => vmcnt(12); tail
// t=17 (no stage(18)): newer-than-stage(17) = A(17) 8 => vmcnt(8).
__global__ __launch_bounds__(256, 3) void gemm_k(const unsigned short* __restrict__ xp,
                                                 const unsigned short* __restrict__ w_t2,
                                                 const float* __restrict__ po,
                                                 const float* __restrict__ thresh,
                                                 const float* __restrict__ scale,
                                                 float* __restrict__ out) {
  __shared__ __align__(16) char sMem[2 * 16384];  // B only, double-buffered

  const int tid = threadIdx.x;
  const int lane = tid & 63;
  const int wid = tid >> 6;  // 0..3
  const int wm = wid >> 1;   // 0..1 (cout half of 128)
  const int wn = wid & 1;    // 0..1 (pixel half of 128)

  // XCD-chunked bijective swizzle: nwg=1568=8*196; cout-pair adjacent
  const int bid = blockIdx.x;
  const int sb = (bid & 7) * 196 + (bid >> 3);
  const int m0 = (sb & 1) << 7;   // 0 or 128
  const int n0 = (sb >> 1) << 7;  // pixel tile base

  // ---- B staging addresses (linear LDS dest + inverse-swizzled source) ----
  const int l8 = lane >> 3;  // row within 8-row chunk
  const int ls = lane & 7;   // 16B slot within 128B row
  const int sw = (ls ^ l8) << 4;
  const char* xpc = (const char*)xp;
  int bSrc[4];
#pragma unroll
  for (int c = 0; c < 4; ++c) {
    int n = n0 + wid * 32 + c * 8 + l8;
    int b = n / HW2, rr = n - b * HW2;
    int h = rr / HW, w = rr - h * HW;
    bSrc[c] = ((b * PH + h + 1) * PH + (w + 1)) * 256 + sw;
  }
  const int bDst = wid * 4096;  // 4 chunks x 1KB, wave-uniform

  // ---- A fragment chunk base: frag(i,ko) at tile t:
  //  ((t*16 + cbase + i)*2 + ko)*1024 + lane*16 ----
  const int cbase = (m0 >> 4) + wm * 4;
  const char* wa = (const char*)w_t2 + (lane << 4);

  // ---- B fragment read offsets (swizzled) ----
  int bro[4][2];
#pragma unroll
  for (int j = 0; j < 4; ++j)
#pragma unroll
    for (int ko = 0; ko < 2; ++ko) {
      int rowB = wn * 64 + j * 16 + (lane & 15);
      int boc = ko * 64 + ((lane >> 4) << 4);
      bro[j][ko] = rowB * 128 + (boc ^ ((rowB & 7) << 4));
    }

  auto STAGEB = [&](int buf, int t) {
    const int p = t >> 1;            // tap 0..8
    const int ch = (t & 1) << 7;     // c-half byte offset
    const int dy = p / 3 - 1, dx = p - (p / 3) * 3 - 1;
    const int offB = ((dy * PH + dx) << 8) + ch;
    char* base = sMem + buf * 16384;
#pragma unroll
    for (int c = 0; c < 4; ++c)
      GLD_LDS16(xpc + bSrc[c] + offB, base + bDst + c * 1024);
  };

#define LOADA(A, t)                                                         \
  {                                                                         \
    _Pragma("unroll") for (int i_ = 0; i_ < 4; ++i_)                        \
        _Pragma("unroll") for (int ko_ = 0; ko_ < 2; ++ko_)                 \
        A[i_ * 2 + ko_] = *reinterpret_cast<const f16x8*>(                  \
            wa + (size_t)(((t)*16 + cbase + i_) * 2 + ko_) * 1024);         \
  }

  f32x4 acc[4][4] = {};
  f16x8 pa[8];

  STAGEB(0, 0);
  __syncthreads();  // drains stage(0)

  for (int t = 0; t < 18; ++t) {
    const char* base = sMem + (t & 1) * 16384;
    __builtin_amdgcn_s_barrier();  // B1: reads of buf^1 (iter t-1) complete
    if (t < 17) {
      STAGEB((t + 1) & 1, t + 1);
      LOADA(pa, t)
      asm volatile("s_waitcnt vmcnt(12)" ::: "memory");  // stage(t) landed
    } else {
      LOADA(pa, t)
      asm volatile("s_waitcnt vmcnt(8)" ::: "memory");   // stage(17) landed
    }
    __builtin_amdgcn_s_barrier();  // B2: everyone's stage(t) landed

    f16x8 bfr[4][2];
#pragma unroll
    for (int j = 0; j < 4; ++j)
#pragma unroll
      for (int ko = 0; ko < 2; ++ko)
        bfr[j][ko] = *reinterpret_cast<const f16x8*>(base + bro[j][ko]);
#pragma unroll
    for (int i = 0; i < 4; ++i) {
      __builtin_amdgcn_s_setprio(1);
#pragma unroll
      for (int j = 0; j < 4; ++j) {
        acc[i][j] = __builtin_amdgcn_mfma_f32_16x16x32_f16(pa[i * 2], bfr[j][0], acc[i][j], 0, 0, 0);
        acc[i][j] = __builtin_amdgcn_mfma_f32_16x16x32_f16(pa[i * 2 + 1], bfr[j][1], acc[i][j], 0, 0, 0);
      }
      __builtin_amdgcn_s_setprio(0);
    }
  }
#undef LOADA

  const float sc = scale[0];
#pragma unroll
  for (int j = 0; j < 4; ++j) {
    int n = n0 + wn * 64 + j * 16 + (lane & 15);
    int b = n / HW2;
    int r = n - b * HW2;  // ho*56+wo
    float pv = po[n];
    float* op = out + (size_t)b * (COUT * HW2) + r;
#pragma unroll
    for (int i = 0; i < 4; ++i) {
      int cl = m0 + wm * 64 + i * 16 + ((lane >> 4) << 2);
      f32x4 th = *reinterpret_cast<const f32x4*>(&thresh[cl]);
#pragma unroll
      for (int q = 0; q < 4; ++q) {
        float cv = acc[i][j][q];
        float g = 1.f / (1.f + __expf(-sc * (cv - th[q])));
        op[(size_t)(cl + q) * HW2] = cv + g * pv;
      }
    }
  }
}

extern "C" void kernel_launch(void* const* d_in, const int* in_sizes, int n_in,
                              void* d_out, int out_size, void* d_ws, size_t ws_size,
                              hipStream_t stream) {
  (void)in_sizes; (void)n_in; (void)out_size; (void)ws_size;
  const float* x      = (const float*)d_in[0];
  const float* core   = (const float*)d_in[1];
  const float* per    = (const float*)d_in[2];
  const float* thresh = (const float*)d_in[3];
  const float* scale  = (const float*)d_in[4];
  float* out = (float*)d_out;

  char* ws = (char*)d_ws;
  unsigned short* xp   = (unsigned short*)ws;                  // 27,557,888 B
  unsigned short* w_t2 = (unsigned short*)(ws + 27557888);     // 589,824 B
  float* xs            = (float*)(ws + 28147712);              // 401,408 B
  float* po            = (float*)(ws + 28549120);              // 401,408 B

  // fused prep: 1792 x-transpose blocks + 456 halo blocks + 144 w_t2 blocks
  prep_x<<<NB * HW + 456 + 144, 256, 0, stream>>>(x, core, xp, w_t2, xs);
  periph_k<<<NPIX / 256, 256, 0, stream>>>(xs, per, po);
  gemm_k<<<2 * (NPIX / 128), 256, 0, stream>>>(xp, w_t2, po, thresh, scale, out);
}